// Round 16
// baseline (86.613 us; speedup 1.0000x reference)
//
#include <hip/hip_runtime.h>
#include <hip/hip_cooperative_groups.h>

namespace cg = cooperative_groups;

#define BB 8
#define NN 128
#define ND 64
#define LL 512
#define RD 1024
#define CG 128
#define HID 192

typedef __attribute__((ext_vector_type(8))) short short8;
typedef __attribute__((ext_vector_type(4))) float f32x4;

__device__ __forceinline__ unsigned short f2bf(float x) {
    unsigned u = __builtin_bit_cast(unsigned, x);
    u += 0x7fffu + ((u >> 16) & 1u);          // RNE
    return (unsigned short)(u >> 16);
}
__device__ __forceinline__ float bf2f(unsigned short h) {
    unsigned u = ((unsigned)h) << 16;
    return __builtin_bit_cast(float, u);
}
#define MFMA __builtin_amdgcn_mfma_f32_16x16x32_bf16

// LDS layout (139KB static; phase-dependent aliasing):
//  GEMM phase (all blocks):  aT @0 (33024) | pbuf @33024 (24576) | h1 @57600 (52224)
//  GNN producer (blk 17-24): hT @0 | mbuf @34816 | WgT @53248 | W1T @88064 |
//                            snorm @140288 | b1c @140800 | sbg @141568
//  WcT producer (blk 0-15):  W1Tw @57600 (no overlap with its pre-staged aT @0)
#define OFF_PBUF  33024
#define OFF_H1    57600
#define OFF_MBUF  34816
#define OFF_WGT   53248
#define OFF_W1T   88064
#define OFF_SNORM 140288
#define OFF_B1C   140800
#define OFF_SBG   141568

// ---------------------------------------------------------------------------
// KMEGA, cooperative, grid 256 x 512 (1 block/CU, all co-resident):
//  Phase A: blk 0..15 WcT via MFMA; blk 16 consts (vbuf, out=cconst);
//           blk 17..24 full per-batch GNN (R14-verified). All non-GNN blocks
//           ALSO pre-stage their GEMM A-tile (prot f32->bf16) into LDS,
//           overlapping the 16.8MB prot read with producer compute.
//  grid.sync()
//  Phase B: everyone (GNN blocks stage aT late), stage h1 bf16, then
//           R14-verified K-split GEMM + fused pairsum epilogue; one
//           atomicAdd(&out[b]) per block.
// ---------------------------------------------------------------------------
__global__ __launch_bounds__(512, 1) void kmega(
    const float* __restrict__ adj, const float* __restrict__ nodes,
    const float* __restrict__ prot,
    const float* __restrict__ Wn, const float* __restrict__ bn,
    const float* __restrict__ Wr, const float* __restrict__ br,
    const float* __restrict__ W1, const float* __restrict__ b1,
    const float* __restrict__ Wg, const float* __restrict__ bg,
    const float* __restrict__ W2, const float* __restrict__ b2,
    const float* __restrict__ Wo, const float* __restrict__ bo,
    unsigned short* __restrict__ WcT, unsigned short* __restrict__ hW1b,
    float* __restrict__ vbuf, float* __restrict__ out)
{
    __shared__ char smem[142080];
    __shared__ float sred[8];
    int t = threadIdx.x, blk = blockIdx.x;
    int w = t >> 6, l = t & 63, lr = l & 15, ks = l >> 4, lk = ks * 8;
    const float* W1b = W1 + CG * HID;

    unsigned short* aT = (unsigned short*)smem;            // [16][1032]
    float* pbuf = (float*)(smem + OFF_PBUF);               // [2][16][192]
    unsigned short* h1 = (unsigned short*)(smem + OFF_H1); // [192][136]

    int bg_ = blk >> 5, lc = blk & 31;    // this block's GEMM tile

    // ================= Phase A =================
    if (blk < 17 || blk >= 25) {
        // pre-stage A: 16 rows x 1024 f32 -> bf16, fully coalesced
        #pragma unroll
        for (int q = 0; q < 4; ++q) {
            int e = t + 512 * q;               // units of 8 floats
            int row = e >> 7;
            int c8 = (e & 127) * 8;
            const float* pr = prot + ((size_t)(bg_ * LL + lc * 16 + row)) * RD + c8;
            float4 p0 = *(const float4*)pr;
            float4 p1 = *(const float4*)(pr + 4);
            unsigned short u[8];
            u[0]=f2bf(p0.x); u[1]=f2bf(p0.y); u[2]=f2bf(p0.z); u[3]=f2bf(p0.w);
            u[4]=f2bf(p1.x); u[5]=f2bf(p1.y); u[6]=f2bf(p1.z); u[7]=f2bf(p1.w);
            *(short8*)(aT + row * 1032 + c8) = *(const short8*)u;
        }
    }

    if (blk < 16) {
        // ---- WcT producer: 64 k-rows via MFMA ----
        unsigned short (*W1Tw)[136] = (unsigned short(*)[136])(smem + OFF_H1);
        int r0 = blk * 64;
        #pragma unroll
        for (int q = 0; q < 48; ++q) {
            int e = t + 512 * q;              // 0..24575
            int m = e / HID, c = e % HID;
            W1Tw[c][m] = f2bf(W1[(size_t)(CG + m) * HID + c]);
        }
        int rt = w & 3, jh = w >> 2;
        short8 awr[4];
        #pragma unroll
        for (int kk = 0; kk < 4; ++kk) {
            const float* wp = Wr + (size_t)(r0 + rt * 16 + lr) * CG + kk * 32 + lk;
            float4 q0 = *(const float4*)wp;
            float4 q1 = *(const float4*)(wp + 4);
            unsigned short u[8];
            u[0]=f2bf(q0.x); u[1]=f2bf(q0.y); u[2]=f2bf(q0.z); u[3]=f2bf(q0.w);
            u[4]=f2bf(q1.x); u[5]=f2bf(q1.y); u[6]=f2bf(q1.z); u[7]=f2bf(q1.w);
            awr[kk] = *(const short8*)u;
        }
        __syncthreads();
        #pragma unroll
        for (int jt6 = 0; jt6 < 6; ++jt6) {
            int jt = jh * 6 + jt6;            // 0..11
            f32x4 d = {0.f, 0.f, 0.f, 0.f};
            #pragma unroll
            for (int kk = 0; kk < 4; ++kk) {
                short8 bf = *(const short8*)(&W1Tw[jt * 16 + lr][kk * 32 + lk]);
                d = MFMA(awr[kk], bf, d, 0, 0, 0);
            }
            unsigned short u[4];
            #pragma unroll
            for (int i = 0; i < 4; ++i) u[i] = f2bf(d[i]);
            *(uint2*)(WcT + (size_t)(jt * 16 + lr) * RD + r0 + rt * 16 + ks * 4) = *(uint2*)u;
        }
    } else if (blk == 16) {
        if (t < HID) {
            float s = 0.f;
            #pragma unroll 8
            for (int k = 0; k < CG; ++k) s = fmaf(W2[t * CG + k], Wo[k], s);
            vbuf[t] = s;
        }
        if (t < BB) {
            float s = 0.f;
            for (int k = 0; k < CG; ++k) s = fmaf(b2[k], Wo[k], s);
            out[t] = (float)(NN * LL) * s + bo[0];   // cconst base
        }
    } else if (blk < 25) {
        // ---- GNN producer, batch b (R14-verified body) ----
        unsigned short (*hT)[136] = (unsigned short(*)[136])smem;
        unsigned short (*mbuf)[72] = (unsigned short(*)[72])(smem + OFF_MBUF);
        unsigned short (*WgT)[136] = (unsigned short(*)[136])(smem + OFF_WGT);
        unsigned short (*W1T)[136] = (unsigned short(*)[136])(smem + OFF_W1T);
        float* snorm = (float*)(smem + OFF_SNORM);
        float* b1cL  = (float*)(smem + OFF_B1C);
        float* sbg   = (float*)(smem + OFF_SBG);
        int b = blk - 17;
        int i0 = w * 16;

        // P0: degrees ; b1c ; stage bg
        {
            float* dscr = (float*)&mbuf[0][0];   // [128][4] f32
            int row = t >> 2, q4 = t & 3;
            const float* ar = adj + ((size_t)b * NN + row) * NN + q4 * 32;
            float d = 0.f;
            #pragma unroll
            for (int c4 = 0; c4 < 8; ++c4) {
                float4 p = *(const float4*)(ar + c4 * 4);
                d += (p.x + p.y) + (p.z + p.w);
            }
            dscr[row * 4 + q4] = d;
            __syncthreads();
            if (t < NN) {
                snorm[t] = rsqrtf(fmaxf(dscr[t*4] + dscr[t*4+1] + dscr[t*4+2] + dscr[t*4+3], 1.f));
            } else if (t < 320) {
                int j = t - 128;
                float s = b1[j];
                #pragma unroll 8
                for (int m = 0; m < CG; ++m)
                    s = fmaf(br[m], W1b[(size_t)m * HID + j], s);
                b1cL[j] = s;
            } else if (t < 448) {
                sbg[t - 320] = bg[t - 320];
            }
            __syncthreads();
        }

        // P1: stage WnT (mbuf), WgT, W1T (R14 scalar-coalesced form)
        unsigned short* WnT = &mbuf[0][0];       // [128][72]
        #pragma unroll
        for (int q = 0; q < 16; ++q) {
            int e = t + 512 * q;
            int c = e & 127, k = e >> 7;
            WnT[c * 72 + k] = f2bf(Wn[(size_t)k * CG + c]);
        }
        #pragma unroll
        for (int q = 0; q < 32; ++q) {
            int e = t + 512 * q;
            int c = e & 127, j = e >> 7;
            WgT[c][j] = f2bf(Wg[(size_t)j * CG + c]);
        }
        #pragma unroll
        for (int q = 0; q < 32; ++q) {
            int e = t + 512 * q;
            int jj = e & 127, k = e >> 7;
            W1T[jj][k] = f2bf(W1[(size_t)k * HID + jj]);
        }
        #pragma unroll
        for (int q = 0; q < 16; ++q) {
            int e = t + 512 * q;
            int jj = 128 + (e & 63), k = e >> 6;
            W1T[jj][k] = f2bf(W1[(size_t)k * HID + jj]);
        }

        // adjn fragments: adjn[i][k] = adj[i][k]*norm[i]*norm[k]
        short8 af[4];
        {
            float ni = snorm[i0 + lr];
            const float* ar = adj + ((size_t)b * NN + i0 + lr) * NN;
            #pragma unroll
            for (int kk = 0; kk < 4; ++kk) {
                int kb = kk * 32 + lk;
                float4 p0 = *(const float4*)(ar + kb);
                float4 p1 = *(const float4*)(ar + kb + 4);
                unsigned short u[8];
                u[0] = f2bf(p0.x * ni * snorm[kb+0]); u[1] = f2bf(p0.y * ni * snorm[kb+1]);
                u[2] = f2bf(p0.z * ni * snorm[kb+2]); u[3] = f2bf(p0.w * ni * snorm[kb+3]);
                u[4] = f2bf(p1.x * ni * snorm[kb+4]); u[5] = f2bf(p1.y * ni * snorm[kb+5]);
                u[6] = f2bf(p1.z * ni * snorm[kb+6]); u[7] = f2bf(p1.w * ni * snorm[kb+7]);
                af[kk] = *(const short8*)u;
            }
        }
        short8 bnod[2];
        #pragma unroll
        for (int kk = 0; kk < 2; ++kk) {
            const float* np = nodes + ((size_t)b * NN + i0 + lr) * ND + kk * 32 + lk;
            float4 q0 = *(const float4*)np;
            float4 q1 = *(const float4*)(np + 4);
            unsigned short u[8];
            u[0]=f2bf(q0.x); u[1]=f2bf(q0.y); u[2]=f2bf(q0.z); u[3]=f2bf(q0.w);
            u[4]=f2bf(q1.x); u[5]=f2bf(q1.y); u[6]=f2bf(q1.z); u[7]=f2bf(q1.w);
            bnod[kk] = *(const short8*)u;
        }
        __syncthreads();

        // P2: h0 -> hT[c][n]
        #pragma unroll
        for (int ct = 0; ct < 8; ++ct) {
            f32x4 d = {0.f, 0.f, 0.f, 0.f};
            #pragma unroll
            for (int kk = 0; kk < 2; ++kk) {
                short8 afw = *(const short8*)(WnT + (ct * 16 + lr) * 72 + kk * 32 + lk);
                d = MFMA(afw, bnod[kk], d, 0, 0, 0);
            }
            #pragma unroll
            for (int i = 0; i < 4; ++i)
                hT[ct * 16 + ks * 4 + i][i0 + lr] = f2bf(d[i] + bn[ct * 16 + ks * 4 + i]);
        }
        __syncthreads();

        // P3: 3 GNN steps
        for (int s = 0; s < 3; ++s) {
            f32x4 acc8[8];
            #pragma unroll
            for (int ct = 0; ct < 8; ++ct) acc8[ct] = (f32x4){0.f, 0.f, 0.f, 0.f};
            #pragma unroll
            for (int hf = 0; hf < 2; ++hf) {
                #pragma unroll
                for (int jt = 0; jt < 4; ++jt) {
                    int jg = hf * 64 + jt * 16;
                    f32x4 d = {0.f, 0.f, 0.f, 0.f};
                    #pragma unroll
                    for (int kk = 0; kk < 4; ++kk) {
                        short8 bf = *(const short8*)(&hT[jg + lr][kk * 32 + lk]);
                        d = MFMA(af[kk], bf, d, 0, 0, 0);
                    }
                    #pragma unroll
                    for (int i = 0; i < 4; ++i)
                        mbuf[i0 + ks * 4 + i][jt * 16 + lr] = f2bf(d[i]);
                }
                short8 bm[2];
                #pragma unroll
                for (int kk = 0; kk < 2; ++kk)
                    bm[kk] = *(const short8*)(&mbuf[i0 + lr][kk * 32 + lk]);
                #pragma unroll
                for (int ct = 0; ct < 8; ++ct) {
                    #pragma unroll
                    for (int kk = 0; kk < 2; ++kk) {
                        short8 wf = *(const short8*)(&WgT[ct * 16 + lr][hf * 64 + kk * 32 + lk]);
                        if (s < 2)
                            acc8[ct] = MFMA(wf, bm[kk], acc8[ct], 0, 0, 0);
                        else
                            acc8[ct] = MFMA(bm[kk], wf, acc8[ct], 0, 0, 0);
                    }
                }
            }
            __syncthreads();
            if (s < 2) {
                #pragma unroll
                for (int ct = 0; ct < 8; ++ct)
                    #pragma unroll
                    for (int i = 0; i < 4; ++i)
                        hT[ct * 16 + ks * 4 + i][i0 + lr] =
                            f2bf(fmaxf(acc8[ct][i] + sbg[ct * 16 + ks * 4 + i], 0.f));
            } else {
                #pragma unroll
                for (int ct = 0; ct < 8; ++ct)
                    #pragma unroll
                    for (int i = 0; i < 4; ++i)
                        hT[i0 + ks * 4 + i][ct * 16 + lr] =
                            f2bf(tanhf(acc8[ct][i] + sbg[ct * 16 + lr]));
            }
            __syncthreads();
        }

        // P4: hW1b[jj][n] = bf16(W1topT @ tanh-h + b1c)
        {
            short8 bh[4];
            #pragma unroll
            for (int kk = 0; kk < 4; ++kk)
                bh[kk] = *(const short8*)(&hT[i0 + lr][kk * 32 + lk]);
            #pragma unroll
            for (int jjt = 0; jjt < 12; ++jjt) {
                f32x4 d = {0.f, 0.f, 0.f, 0.f};
                #pragma unroll
                for (int kk = 0; kk < 4; ++kk) {
                    short8 wf = *(const short8*)(&W1T[jjt * 16 + lr][kk * 32 + lk]);
                    d = MFMA(wf, bh[kk], d, 0, 0, 0);
                }
                #pragma unroll
                for (int i = 0; i < 4; ++i) {
                    int jj = jjt * 16 + ks * 4 + i;
                    hW1b[(size_t)b * HID * NN + jj * NN + i0 + lr] = f2bf(d[i] + b1cL[jj]);
                }
            }
        }
    }

    cg::this_grid().sync();

    // ================= Phase B (all blocks) =================
    if (blk >= 17 && blk < 25) {
        // late A-stage for GNN blocks (their LDS was busy in phase A)
        #pragma unroll
        for (int q = 0; q < 4; ++q) {
            int e = t + 512 * q;
            int row = e >> 7;
            int c8 = (e & 127) * 8;
            const float* pr = prot + ((size_t)(bg_ * LL + lc * 16 + row)) * RD + c8;
            float4 p0 = *(const float4*)pr;
            float4 p1 = *(const float4*)(pr + 4);
            unsigned short u[8];
            u[0]=f2bf(p0.x); u[1]=f2bf(p0.y); u[2]=f2bf(p0.z); u[3]=f2bf(p0.w);
            u[4]=f2bf(p1.x); u[5]=f2bf(p1.y); u[6]=f2bf(p1.z); u[7]=f2bf(p1.w);
            *(short8*)(aT + row * 1032 + c8) = *(const short8*)u;
        }
    }
    // stage h1 (bf16 short8 copy) -- R14-verified
    #pragma unroll
    for (int q = 0; q < 6; ++q) {
        int u8 = t + 512 * q;                  // units of 8 bf16
        int row = u8 >> 4;                     // 0..191
        int n8 = (u8 & 15) * 8;                // 0..120
        short8 v = *(const short8*)(hW1b + (size_t)bg_ * HID * NN + row * NN + n8);
        *(short8*)(h1 + row * 136 + n8) = v;
    }
    int w2 = w >> 2, wj = w & 3;
    float v0 = vbuf[wj * 48 + lr];
    float v1 = vbuf[wj * 48 + 16 + lr];
    float v2 = vbuf[wj * 48 + 32 + lr];
    __syncthreads();

    // GEMM: K-half per w2 (R14-verified)
    f32x4 a0 = {0.f,0.f,0.f,0.f}, a1 = a0, a2 = a0;
    {
        const unsigned short* ap = aT + lr * 1032 + w2 * 512 + lk;
        const unsigned short* bp = WcT + (size_t)(wj * 48 + lr) * RD + w2 * 512 + lk;
        #pragma unroll 4
        for (int k0 = 0; k0 < 512; k0 += 32) {
            short8 av = *(const short8*)(ap + k0);
            short8 b0 = *(const short8*)(bp + k0);
            short8 b1v = *(const short8*)(bp + 16 * RD + k0);
            short8 b2v = *(const short8*)(bp + 32 * RD + k0);
            a0 = MFMA(av, b0, a0, 0, 0, 0);
            a1 = MFMA(av, b1v, a1, 0, 0, 0);
            a2 = MFMA(av, b2v, a2, 0, 0, 0);
        }
    }
    #pragma unroll
    for (int i = 0; i < 4; ++i) {
        int r = ks * 4 + i;
        pbuf[(w2 * 16 + r) * 192 + wj * 48 + lr]      = a0[i];
        pbuf[(w2 * 16 + r) * 192 + wj * 48 + 16 + lr] = a1[i];
        pbuf[(w2 * 16 + r) * 192 + wj * 48 + 32 + lr] = a2[i];
    }
    __syncthreads();
    float rw0[4], rw1[4], rw2[4];
    #pragma unroll
    for (int i = 0; i < 4; ++i) {
        int r = ks * 4 + i;
        rw0[i] = pbuf[r * 192 + wj*48 + lr]      + pbuf[(16 + r) * 192 + wj*48 + lr];
        rw1[i] = pbuf[r * 192 + wj*48 + 16 + lr] + pbuf[(16 + r) * 192 + wj*48 + 16 + lr];
        rw2[i] = pbuf[r * 192 + wj*48 + 32 + lr] + pbuf[(16 + r) * 192 + wj*48 + 32 + lr];
    }

    // fused pairsum epilogue over n-half w2 (h1 in LDS) -- R14-verified
    const unsigned short* h0p = h1 + (wj * 48 + lr) * 136 + w2 * 64;
    const unsigned short* h1p = h0p + 16 * 136;
    const unsigned short* h2p = h0p + 32 * 136;
    float s = 0.f;
    #pragma unroll 2
    for (int n0 = 0; n0 < 64; n0 += 4) {
        unsigned short e0[4], e1[4], e2[4];
        *(uint2*)e0 = *(const uint2*)(h0p + n0);
        *(uint2*)e1 = *(const uint2*)(h1p + n0);
        *(uint2*)e2 = *(const uint2*)(h2p + n0);
        #pragma unroll
        for (int q = 0; q < 4; ++q) {
            float hh0 = bf2f(e0[q]), hh1 = bf2f(e1[q]), hh2 = bf2f(e2[q]);
            #pragma unroll
            for (int i = 0; i < 4; ++i) {
                s = fmaf(v0, fmaxf(rw0[i] + hh0, 0.f), s);
                s = fmaf(v1, fmaxf(rw1[i] + hh1, 0.f), s);
                s = fmaf(v2, fmaxf(rw2[i] + hh2, 0.f), s);
            }
        }
    }
    for (int off = 32; off; off >>= 1) s += __shfl_down(s, off);
    if (l == 0) sred[w] = s;
    __syncthreads();
    if (t == 0) {
        float tot = ((sred[0] + sred[1]) + (sred[2] + sred[3]))
                  + ((sred[4] + sred[5]) + (sred[6] + sred[7]));
        atomicAdd(&out[bg_], tot);
    }
}

extern "C" void kernel_launch(void* const* d_in, const int* in_sizes, int n_in,
                              void* d_out, int out_size, void* d_ws, size_t ws_size,
                              hipStream_t stream)
{
    const float* adj   = (const float*)d_in[0];
    const float* nodes = (const float*)d_in[1];
    const float* prot  = (const float*)d_in[2];
    const float* Wn    = (const float*)d_in[3];
    const float* bn    = (const float*)d_in[4];
    const float* Wg    = (const float*)d_in[5];
    const float* bg    = (const float*)d_in[6];
    const float* Wr    = (const float*)d_in[7];
    const float* br    = (const float*)d_in[8];
    // d_in[9]=Wa, d_in[10]=ba: unused (softmax over size-1 axis == 1)
    const float* W1    = (const float*)d_in[11];
    const float* b1    = (const float*)d_in[12];
    const float* W2    = (const float*)d_in[13];
    const float* b2    = (const float*)d_in[14];
    const float* Wo    = (const float*)d_in[15];
    const float* bo    = (const float*)d_in[16];

    float* ws     = (float*)d_ws;
    float* vbuf   = ws;                                   // [192]
    unsigned short* hW1b = (unsigned short*)(ws + 192);   // [8][192][128] bf16
    unsigned short* WcT  = hW1b + (size_t)BB * HID * NN;  // [192][1024] bf16
    float* outp   = (float*)d_out;

    void* kargs[] = {
        (void*)&adj, (void*)&nodes, (void*)&prot,
        (void*)&Wn, (void*)&bn, (void*)&Wr, (void*)&br,
        (void*)&W1, (void*)&b1, (void*)&Wg, (void*)&bg,
        (void*)&W2, (void*)&b2, (void*)&Wo, (void*)&bo,
        (void*)&WcT, (void*)&hW1b, (void*)&vbuf, (void*)&outp
    };
    hipLaunchCooperativeKernel((const void*)kmega, dim3(256), dim3(512),
                               kargs, 0, stream);
}

// Round 17
// 53.127 us; speedup vs baseline: 1.6303x; 1.6303x over previous
//
#include <hip/hip_runtime.h>
#include <hip/hip_bf16.h>

#define BB 8
#define NN 128
#define ND 64
#define LL 512
#define RD 1024
#define CG 128
#define HID 192

typedef __attribute__((ext_vector_type(8))) short short8;
typedef __attribute__((ext_vector_type(4))) float f32x4;

// HW bf16 convert (v_cvt_pk_bf16_f32, RNE) - 1 instr vs 5 for bit-twiddle
__device__ __forceinline__ unsigned short f2bf(float x) {
    return __bfloat16_as_ushort(__float2bfloat16(x));
}
__device__ __forceinline__ float bf2f(unsigned short h) {
    unsigned u = ((unsigned)h) << 16;
    return __builtin_bit_cast(float, u);
}
// branch-free tanh: 1 - 2/(e^{2x}+1); saturates correctly at +-1
__device__ __forceinline__ float fast_tanh(float x) {
    float e = __expf(2.0f * x);
    return 1.0f - 2.0f * __builtin_amdgcn_rcpf(e + 1.0f);
}
#define MFMA __builtin_amdgcn_mfma_f32_16x16x32_bf16

// ---------------------------------------------------------------------------
// K_PREP, grid 25 x 512 (139KB LDS, 1 block/CU; all co-resident):
//  blk 0..15 : WcT[c][k] = bf16((Wr@W1b)[k][c]) via MFMA, 64 k-rows/block.
//  blk 16    : vbuf = W2@Wo ; out[b] = cconst (base for k_gemm atomics)
//  blk 17..24: per-batch GNN, all-MFMA, weights staged once in LDS,
//              norms folded into adjn (regs). Writes hW1b[b][192][128] bf16.
// ---------------------------------------------------------------------------
__global__ __launch_bounds__(512, 1) void k_prep(
    const float* __restrict__ adj, const float* __restrict__ nodes,
    const float* __restrict__ Wn, const float* __restrict__ bn,
    const float* __restrict__ Wr, const float* __restrict__ br,
    const float* __restrict__ W1, const float* __restrict__ b1,
    const float* __restrict__ Wg, const float* __restrict__ bg,
    const float* __restrict__ W2, const float* __restrict__ b2,
    const float* __restrict__ Wo, const float* __restrict__ bo,
    unsigned short* __restrict__ WcT, unsigned short* __restrict__ hW1b,
    float* __restrict__ vbuf, float* __restrict__ out)
{
    __shared__ unsigned short hT[NN][136];    // 34.8KB h (feature-major / node-major)
    __shared__ unsigned short mbuf[NN][72];   // 18.4KB m half / WnT / deg scratch
    __shared__ unsigned short WgT[NN][136];   // 34.8KB WgT[c][j]
    __shared__ unsigned short W1T[HID][136];  // 52.2KB W1T[jj][k] (W1bT in WcT blocks)
    __shared__ float snorm[NN];
    __shared__ float b1cL[HID];
    __shared__ float sbg[NN];
    int t = threadIdx.x, blk = blockIdx.x;
    int w = t >> 6, l = t & 63, lr = l & 15, ks = l >> 4, lk = ks * 8;
    const float* W1b = W1 + CG * HID;

    if (blk < 16) {
        int r0 = blk * 64;
        #pragma unroll
        for (int q = 0; q < 48; ++q) {
            int e = t + 512 * q;              // 0..24575
            int m = e / HID, c = e % HID;
            W1T[c][m] = f2bf(W1[(size_t)(CG + m) * HID + c]);
        }
        int rt = w & 3, jh = w >> 2;
        short8 awr[4];
        #pragma unroll
        for (int kk = 0; kk < 4; ++kk) {
            const float* wp = Wr + (size_t)(r0 + rt * 16 + lr) * CG + kk * 32 + lk;
            float4 q0 = *(const float4*)wp;
            float4 q1 = *(const float4*)(wp + 4);
            unsigned short u[8];
            u[0]=f2bf(q0.x); u[1]=f2bf(q0.y); u[2]=f2bf(q0.z); u[3]=f2bf(q0.w);
            u[4]=f2bf(q1.x); u[5]=f2bf(q1.y); u[6]=f2bf(q1.z); u[7]=f2bf(q1.w);
            awr[kk] = *(const short8*)u;
        }
        __syncthreads();
        #pragma unroll
        for (int jt6 = 0; jt6 < 6; ++jt6) {
            int jt = jh * 6 + jt6;            // 0..11
            f32x4 d = {0.f, 0.f, 0.f, 0.f};
            #pragma unroll
            for (int kk = 0; kk < 4; ++kk) {
                short8 bf = *(const short8*)(&W1T[jt * 16 + lr][kk * 32 + lk]);
                d = MFMA(awr[kk], bf, d, 0, 0, 0);
            }
            unsigned short u[4];
            #pragma unroll
            for (int i = 0; i < 4; ++i) u[i] = f2bf(d[i]);
            *(uint2*)(WcT + (size_t)(jt * 16 + lr) * RD + r0 + rt * 16 + ks * 4) = *(uint2*)u;
        }
        return;
    }
    if (blk == 16) {
        if (t < HID) {
            float s = 0.f;
            #pragma unroll 8
            for (int k = 0; k < CG; ++k) s = fmaf(W2[t * CG + k], Wo[k], s);
            vbuf[t] = s;
        }
        if (t < BB) {
            float s = 0.f;
            for (int k = 0; k < CG; ++k) s = fmaf(b2[k], Wo[k], s);
            out[t] = (float)(NN * LL) * s + bo[0];   // cconst base
        }
        return;
    }

    // ---------------- GNN block, batch b ----------------
    int b = blk - 17;
    int i0 = w * 16;

    // P0: degrees (scratch in mbuf) ; b1c ; stage bg
    {
        float* dscr = (float*)&mbuf[0][0];   // [128][4] f32
        int row = t >> 2, q4 = t & 3;
        const float* ar = adj + ((size_t)b * NN + row) * NN + q4 * 32;
        float d = 0.f;
        #pragma unroll
        for (int c4 = 0; c4 < 8; ++c4) {
            float4 p = *(const float4*)(ar + c4 * 4);
            d += (p.x + p.y) + (p.z + p.w);
        }
        dscr[row * 4 + q4] = d;
        __syncthreads();
        if (t < NN) {
            snorm[t] = rsqrtf(fmaxf(dscr[t*4] + dscr[t*4+1] + dscr[t*4+2] + dscr[t*4+3], 1.f));
        } else if (t < 320) {
            int j = t - 128;
            float s = b1[j];
            #pragma unroll 8
            for (int m = 0; m < CG; ++m)
                s = fmaf(br[m], W1b[(size_t)m * HID + j], s);
            b1cL[j] = s;
        } else if (t < 448) {
            sbg[t - 320] = bg[t - 320];
        }
        __syncthreads();
    }

    // P1: stage WnT (mbuf), WgT, W1T into LDS (coalesced reads)
    unsigned short* WnT = &mbuf[0][0];       // [128][72]
    #pragma unroll
    for (int q = 0; q < 16; ++q) {
        int e = t + 512 * q;
        int c = e & 127, k = e >> 7;
        WnT[c * 72 + k] = f2bf(Wn[(size_t)k * CG + c]);
    }
    #pragma unroll
    for (int q = 0; q < 32; ++q) {
        int e = t + 512 * q;
        int c = e & 127, j = e >> 7;
        WgT[c][j] = f2bf(Wg[(size_t)j * CG + c]);
    }
    #pragma unroll
    for (int q = 0; q < 32; ++q) {
        int e = t + 512 * q;
        int jj = e & 127, k = e >> 7;
        W1T[jj][k] = f2bf(W1[(size_t)k * HID + jj]);
    }
    #pragma unroll
    for (int q = 0; q < 16; ++q) {
        int e = t + 512 * q;
        int jj = 128 + (e & 63), k = e >> 6;
        W1T[jj][k] = f2bf(W1[(size_t)k * HID + jj]);
    }

    // adjn fragments: adjn[i][k] = adj[i][k]*norm[i]*norm[k] (bf16, regs)
    short8 af[4];
    {
        float ni = snorm[i0 + lr];
        const float* ar = adj + ((size_t)b * NN + i0 + lr) * NN;
        #pragma unroll
        for (int kk = 0; kk < 4; ++kk) {
            int kb = kk * 32 + lk;
            float4 p0 = *(const float4*)(ar + kb);
            float4 p1 = *(const float4*)(ar + kb + 4);
            unsigned short u[8];
            u[0] = f2bf(p0.x * ni * snorm[kb+0]); u[1] = f2bf(p0.y * ni * snorm[kb+1]);
            u[2] = f2bf(p0.z * ni * snorm[kb+2]); u[3] = f2bf(p0.w * ni * snorm[kb+3]);
            u[4] = f2bf(p1.x * ni * snorm[kb+4]); u[5] = f2bf(p1.y * ni * snorm[kb+5]);
            u[6] = f2bf(p1.z * ni * snorm[kb+6]); u[7] = f2bf(p1.w * ni * snorm[kb+7]);
            af[kk] = *(const short8*)u;
        }
    }
    short8 bnod[2];
    #pragma unroll
    for (int kk = 0; kk < 2; ++kk) {
        const float* np = nodes + ((size_t)b * NN + i0 + lr) * ND + kk * 32 + lk;
        float4 q0 = *(const float4*)np;
        float4 q1 = *(const float4*)(np + 4);
        unsigned short u[8];
        u[0]=f2bf(q0.x); u[1]=f2bf(q0.y); u[2]=f2bf(q0.z); u[3]=f2bf(q0.w);
        u[4]=f2bf(q1.x); u[5]=f2bf(q1.y); u[6]=f2bf(q1.z); u[7]=f2bf(q1.w);
        bnod[kk] = *(const short8*)u;
    }
    __syncthreads();

    // P2: h0 = nodes@Wn + bn -> hT[c][n] feature-major
    #pragma unroll
    for (int ct = 0; ct < 8; ++ct) {
        f32x4 d = {0.f, 0.f, 0.f, 0.f};
        #pragma unroll
        for (int kk = 0; kk < 2; ++kk) {
            short8 afw = *(const short8*)(WnT + (ct * 16 + lr) * 72 + kk * 32 + lk);
            d = MFMA(afw, bnod[kk], d, 0, 0, 0);
        }
        #pragma unroll
        for (int i = 0; i < 4; ++i)
            hT[ct * 16 + ks * 4 + i][i0 + lr] = f2bf(d[i] + bn[ct * 16 + ks * 4 + i]);
    }
    __syncthreads();

    // P3: 3 GNN steps (ds_read_b128 operands)
    for (int s = 0; s < 3; ++s) {
        f32x4 acc8[8];
        #pragma unroll
        for (int ct = 0; ct < 8; ++ct) acc8[ct] = (f32x4){0.f, 0.f, 0.f, 0.f};
        #pragma unroll
        for (int hf = 0; hf < 2; ++hf) {
            #pragma unroll
            for (int jt = 0; jt < 4; ++jt) {
                int jg = hf * 64 + jt * 16;
                f32x4 d = {0.f, 0.f, 0.f, 0.f};
                #pragma unroll
                for (int kk = 0; kk < 4; ++kk) {
                    short8 bf = *(const short8*)(&hT[jg + lr][kk * 32 + lk]);
                    d = MFMA(af[kk], bf, d, 0, 0, 0);
                }
                #pragma unroll
                for (int i = 0; i < 4; ++i)
                    mbuf[i0 + ks * 4 + i][jt * 16 + lr] = f2bf(d[i]);
            }
            short8 bm[2];
            #pragma unroll
            for (int kk = 0; kk < 2; ++kk)
                bm[kk] = *(const short8*)(&mbuf[i0 + lr][kk * 32 + lk]);
            #pragma unroll
            for (int ct = 0; ct < 8; ++ct) {
                #pragma unroll
                for (int kk = 0; kk < 2; ++kk) {
                    short8 wf = *(const short8*)(&WgT[ct * 16 + lr][hf * 64 + kk * 32 + lk]);
                    if (s < 2)
                        acc8[ct] = MFMA(wf, bm[kk], acc8[ct], 0, 0, 0);
                    else
                        acc8[ct] = MFMA(bm[kk], wf, acc8[ct], 0, 0, 0);
                }
            }
        }
        __syncthreads();
        if (s < 2) {
            #pragma unroll
            for (int ct = 0; ct < 8; ++ct)
                #pragma unroll
                for (int i = 0; i < 4; ++i)
                    hT[ct * 16 + ks * 4 + i][i0 + lr] =
                        f2bf(fmaxf(acc8[ct][i] + sbg[ct * 16 + ks * 4 + i], 0.f));
        } else {
            #pragma unroll
            for (int ct = 0; ct < 8; ++ct)
                #pragma unroll
                for (int i = 0; i < 4; ++i)
                    hT[i0 + ks * 4 + i][ct * 16 + lr] =
                        f2bf(fast_tanh(acc8[ct][i] + sbg[ct * 16 + lr]));
        }
        __syncthreads();
    }

    // P4: hW1b[jj][n] = bf16(W1topT @ tanh-h + b1c)
    {
        short8 bh[4];
        #pragma unroll
        for (int kk = 0; kk < 4; ++kk)
            bh[kk] = *(const short8*)(&hT[i0 + lr][kk * 32 + lk]);
        #pragma unroll
        for (int jjt = 0; jjt < 12; ++jjt) {
            f32x4 d = {0.f, 0.f, 0.f, 0.f};
            #pragma unroll
            for (int kk = 0; kk < 4; ++kk) {
                short8 wf = *(const short8*)(&W1T[jjt * 16 + lr][kk * 32 + lk]);
                d = MFMA(wf, bh[kk], d, 0, 0, 0);
            }
            #pragma unroll
            for (int i = 0; i < 4; ++i) {
                int jj = jjt * 16 + ks * 4 + i;
                hW1b[(size_t)b * HID * NN + jj * NN + i0 + lr] = f2bf(d[i] + b1cL[jj]);
            }
        }
    }
}

// ---------------------------------------------------------------------------
// K_GEMM, grid 256 x 512, 2 blocks/CU (4 waves/SIMD), R14-verified:
//  block (b, lc): 16 prot rows, all 192 j. A f32->bf16 staged coalesced;
//  hW1b (bf16) copied via short8. Wave (w2,wj): K-half w2, 48 j-cols.
//  LDS partial combine; fused pairsum epilogue; ONE atomicAdd per block.
// ---------------------------------------------------------------------------
__global__ __launch_bounds__(512, 4) void k_gemm(
    const float* __restrict__ prot, const unsigned short* __restrict__ WcT,
    const unsigned short* __restrict__ hW1b, const float* __restrict__ vbuf,
    float* __restrict__ out)
{
    __shared__ unsigned short aT[16 * 1032];   // 33024B
    __shared__ unsigned short h1[HID * 136];   // 52224B
    __shared__ float pbuf[2 * 16 * 192];       // 24576B -- total 109.8KB, 1/CU
    __shared__ float sred[8];
    int t = threadIdx.x, blk = blockIdx.x;
    int b = blk >> 5, lc = blk & 31;
    int w = t >> 6, l = t & 63, lr = l & 15, ks = l >> 4, lk = ks * 8;
    int w2 = w >> 2, wj = w & 3;

    // stage A: 16 rows x 1024 f32 -> bf16, fully coalesced
    #pragma unroll
    for (int q = 0; q < 4; ++q) {
        int e = t + 512 * q;                   // units of 8 floats
        int row = e >> 7;
        int c8 = (e & 127) * 8;
        const float* pr = prot + ((size_t)(b * LL + lc * 16 + row)) * RD + c8;
        float4 p0 = *(const float4*)pr;
        float4 p1 = *(const float4*)(pr + 4);
        unsigned short u[8];
        u[0]=f2bf(p0.x); u[1]=f2bf(p0.y); u[2]=f2bf(p0.z); u[3]=f2bf(p0.w);
        u[4]=f2bf(p1.x); u[5]=f2bf(p1.y); u[6]=f2bf(p1.z); u[7]=f2bf(p1.w);
        *(short8*)(aT + row * 1032 + c8) = *(const short8*)u;
    }
    // stage hW1b[b] -> LDS: raw bf16 copy, coalesced
    #pragma unroll
    for (int q = 0; q < 6; ++q) {
        int u8 = t + 512 * q;                  // units of 8 bf16
        int row = u8 >> 4;                     // 0..191
        int n8 = (u8 & 15) * 8;                // 0..120
        short8 v = *(const short8*)(hW1b + (size_t)b * HID * NN + row * NN + n8);
        *(short8*)(h1 + row * 136 + n8) = v;
    }
    float v0 = vbuf[wj * 48 + lr];
    float v1 = vbuf[wj * 48 + 16 + lr];
    float v2 = vbuf[wj * 48 + 32 + lr];
    __syncthreads();

    // GEMM: K-half per w2
    f32x4 a0 = {0.f,0.f,0.f,0.f}, a1 = a0, a2 = a0;
    {
        const unsigned short* ap = aT + lr * 1032 + w2 * 512 + lk;
        const unsigned short* bp = WcT + (size_t)(wj * 48 + lr) * RD + w2 * 512 + lk;
        #pragma unroll 4
        for (int k0 = 0; k0 < 512; k0 += 32) {
            short8 av = *(const short8*)(ap + k0);
            short8 b0 = *(const short8*)(bp + k0);
            short8 b1 = *(const short8*)(bp + 16 * RD + k0);
            short8 b2 = *(const short8*)(bp + 32 * RD + k0);
            a0 = MFMA(av, b0, a0, 0, 0, 0);
            a1 = MFMA(av, b1, a1, 0, 0, 0);
            a2 = MFMA(av, b2, a2, 0, 0, 0);
        }
    }
    #pragma unroll
    for (int i = 0; i < 4; ++i) {
        int r = ks * 4 + i;
        pbuf[(w2 * 16 + r) * 192 + wj * 48 + lr]      = a0[i];
        pbuf[(w2 * 16 + r) * 192 + wj * 48 + 16 + lr] = a1[i];
        pbuf[(w2 * 16 + r) * 192 + wj * 48 + 32 + lr] = a2[i];
    }
    __syncthreads();
    float rw0[4], rw1[4], rw2[4];
    #pragma unroll
    for (int i = 0; i < 4; ++i) {
        int r = ks * 4 + i;
        rw0[i] = pbuf[r * 192 + wj*48 + lr]      + pbuf[(16 + r) * 192 + wj*48 + lr];
        rw1[i] = pbuf[r * 192 + wj*48 + 16 + lr] + pbuf[(16 + r) * 192 + wj*48 + 16 + lr];
        rw2[i] = pbuf[r * 192 + wj*48 + 32 + lr] + pbuf[(16 + r) * 192 + wj*48 + 32 + lr];
    }

    // fused pairsum epilogue over n-half w2 (h1 in LDS)
    const unsigned short* h0p = h1 + (wj * 48 + lr) * 136 + w2 * 64;
    const unsigned short* h1p = h0p + 16 * 136;
    const unsigned short* h2p = h0p + 32 * 136;
    float s = 0.f;
    #pragma unroll 2
    for (int n0 = 0; n0 < 64; n0 += 4) {
        unsigned short e0[4], e1[4], e2[4];
        *(uint2*)e0 = *(const uint2*)(h0p + n0);
        *(uint2*)e1 = *(const uint2*)(h1p + n0);
        *(uint2*)e2 = *(const uint2*)(h2p + n0);
        #pragma unroll
        for (int q = 0; q < 4; ++q) {
            float hh0 = bf2f(e0[q]), hh1 = bf2f(e1[q]), hh2 = bf2f(e2[q]);
            #pragma unroll
            for (int i = 0; i < 4; ++i) {
                s = fmaf(v0, fmaxf(rw0[i] + hh0, 0.f), s);
                s = fmaf(v1, fmaxf(rw1[i] + hh1, 0.f), s);
                s = fmaf(v2, fmaxf(rw2[i] + hh2, 0.f), s);
            }
        }
    }
    for (int off = 32; off; off >>= 1) s += __shfl_down(s, off);
    if (l == 0) sred[w] = s;
    __syncthreads();
    if (t == 0) {
        float tot = ((sred[0] + sred[1]) + (sred[2] + sred[3]))
                  + ((sred[4] + sred[5]) + (sred[6] + sred[7]));
        atomicAdd(&out[b], tot);
    }
}

extern "C" void kernel_launch(void* const* d_in, const int* in_sizes, int n_in,
                              void* d_out, int out_size, void* d_ws, size_t ws_size,
                              hipStream_t stream)
{
    const float* adj   = (const float*)d_in[0];
    const float* nodes = (const float*)d_in[1];
    const float* prot  = (const float*)d_in[2];
    const float* Wn    = (const float*)d_in[3];
    const float* bn    = (const float*)d_in[4];
    const float* Wg    = (const float*)d_in[5];
    const float* bg    = (const float*)d_in[6];
    const float* Wr    = (const float*)d_in[7];
    const float* br    = (const float*)d_in[8];
    // d_in[9]=Wa, d_in[10]=ba: unused (softmax over size-1 axis == 1)
    const float* W1    = (const float*)d_in[11];
    const float* b1    = (const float*)d_in[12];
    const float* W2    = (const float*)d_in[13];
    const float* b2    = (const float*)d_in[14];
    const float* Wo    = (const float*)d_in[15];
    const float* bo    = (const float*)d_in[16];

    float* ws     = (float*)d_ws;
    float* vbuf   = ws;                                   // [192]
    unsigned short* hW1b = (unsigned short*)(ws + 192);   // [8][192][128] bf16
    unsigned short* WcT  = hW1b + (size_t)BB * HID * NN;  // [192][1024] bf16
    float* out    = (float*)d_out;

    hipLaunchKernelGGL(k_prep, dim3(25), dim3(512), 0, stream,
                       adj, nodes, Wn, bn, Wr, br, W1, b1, Wg, bg,
                       W2, b2, Wo, bo, WcT, hW1b, vbuf, out);
    hipLaunchKernelGGL(k_gemm, dim3(256), dim3(512), 0, stream,
                       prot, WcT, hW1b, vbuf, out);
}